// Round 6
// baseline (1701.586 us; speedup 1.0000x reference)
//
#include <hip/hip_runtime.h>

// Neighbor search: M=N=12288, DIM=3.
// d_out layout (float32, flat):
//   [0 .. M]                row_splits
//   [M+1 .. M+1+M*N)        mask (0.0 / 1.0)
//   [M+1+M*N .. +2*M*N)     weights (d2 if mask else 0)
//
// R7 = DIAGNOSTIC ROUND 2 (deliberate, accepted regression).
// R6's 2-pass timing: total 1240 -> 1474, marginal pass = +234us = 5.2 TB/s.
// => store stream runs near peak once started; the whole R4-vs-floor gap is
// a ~230us FIXED TRANSIENT on the first pass (T = tax + passes*237us).
// Remaining ambiguity: H-fetch (first-write L2/MALL allocate fetches ~1.2GB
// from DRAM -> attackable) vs H-drain (poison fill's dirty-line drain stalls
// DRAM -> external, unfixable). nbr at ~695us still hid below the ~790us
// fills, so we STILL have no nbr counters. This round: runtime npass=3
// (runtime arg forbids unroll/DSE; R6 timing proves passes execute) ->
// nbr ~935us > all fills -> top-5 = nbr rows with FETCH/WRITE/VALU/Occ.
// Read: FETCH >= ~1.0e6 KB => H-fetch (attack cache policy next);
//       FETCH <= ~2e5 KB  => H-drain (restore R4, declare floor).
//
// Bit-exactness vs numpy/BLAS fp32 (unchanged):
//   sq = (x0*x0 + x1*x1) + x2*x2
//   dot = fma(q2,d2, fma(q1,d1, q0*d0))
//   d2  = (sq_q + sq_d) - 2*dot ; max(d2,0) ; mask = d2 <= r*r
// Passes 2/3 store identical bytes to identical addresses (program order per
// thread) -> final memory image identical; counts only accumulate in pass 0.

#define BLK 256
#define ROWS 8
#define GTILE 512             // float4 column-groups per LDS tile
#define TWORDS (GTILE * 12)   // 6144 floats = 24 KB

typedef float floatx4 __attribute__((ext_vector_type(4)));

__global__ __launch_bounds__(BLK) void nbr_kernel(
    const float* __restrict__ data,
    const float* __restrict__ queries,
    const float* __restrict__ radius_p,
    float* __restrict__ out,
    int* __restrict__ counts,
    int N, long long mask_off, long long w_off, int cbase, int npass)
{
    __shared__ float4 tile4[GTILE * 3];
    float* tile = reinterpret_cast<float*>(tile4);
    __shared__ int lds_cnt[ROWS];

    const int tid = threadIdx.x;
    const int m0 = blockIdx.x * ROWS;

    const float r = radius_p[0];
    const float r2 = __fmul_rn(r, r);

    float q0[ROWS], q1[ROWS], q2[ROWS], sqq[ROWS];
#pragma unroll
    for (int rr = 0; rr < ROWS; ++rr) {
        q0[rr] = queries[3 * (m0 + rr) + 0];
        q1[rr] = queries[3 * (m0 + rr) + 1];
        q2[rr] = queries[3 * (m0 + rr) + 2];
        sqq[rr] = __fadd_rn(__fadd_rn(__fmul_rn(q0[rr], q0[rr]),
                                      __fmul_rn(q1[rr], q1[rr])),
                            __fmul_rn(q2[rr], q2[rr]));
    }

    float* mrow[ROWS];
    float* wrow[ROWS];
#pragma unroll
    for (int rr = 0; rr < ROWS; ++rr) {
        mrow[rr] = out + mask_off + (long long)(m0 + rr) * N;
        wrow[rr] = out + w_off    + (long long)(m0 + rr) * N;
    }

    int cnt[ROWS];
#pragma unroll
    for (int rr = 0; rr < ROWS; ++rr) cnt[rr] = 0;

    const int ng = (N - cbase) / 4;
    const int nspec = N - 4 * ng;  // cols 0..cbase-1 and cbase+4*ng..N-1

    for (int pass = 0; pass < npass; ++pass) {
        // Scalar prologue for the non-line-aligned columns.
        if (tid < nspec) {
            const int c = (tid < cbase) ? tid : (cbase + 4 * ng + (tid - cbase));
            const float d0  = data[3 * c + 0];
            const float d1  = data[3 * c + 1];
            const float d2e = data[3 * c + 2];
            const float sqd = __fadd_rn(
                __fadd_rn(__fmul_rn(d0, d0), __fmul_rn(d1, d1)),
                __fmul_rn(d2e, d2e));
#pragma unroll
            for (int rr = 0; rr < ROWS; ++rr) {
                const float dot = __fmaf_rn(q2[rr], d2e,
                                    __fmaf_rn(q1[rr], d1, __fmul_rn(q0[rr], d0)));
                float v = __fsub_rn(__fadd_rn(sqq[rr], sqd), __fmul_rn(2.0f, dot));
                v = fmaxf(v, 0.0f);
                const bool in = (v <= r2);
                mrow[rr][c] = in ? 1.0f : 0.0f;
                wrow[rr][c] = in ? v : 0.0f;
                if (pass == 0) cnt[rr] += in ? 1 : 0;
            }
        }

        // Main loop over column-group tiles.
        for (int g0 = 0; g0 < ng; g0 += GTILE) {
            const int ngt = min(GTILE, ng - g0);
            const long long W0 = 3LL * (cbase + 4LL * (long long)g0);
            const int lim = 12 * ngt;

            __syncthreads();  // previous tile's readers done before overwrite
            if (lim == TWORDS) {
#pragma unroll
                for (int k = 0; k < TWORDS / BLK; ++k)
                    tile[k * BLK + tid] = data[W0 + k * BLK + tid];
            } else {
                for (int w = tid; w < lim; w += BLK)
                    tile[w] = data[W0 + w];
            }
            __syncthreads();

#pragma unroll
            for (int k = 0; k < GTILE / BLK; ++k) {
                const int sl = k * BLK + tid;
                if (sl < ngt) {
                    const float4 A = tile4[3 * sl + 0];
                    const float4 B = tile4[3 * sl + 1];
                    const float4 C = tile4[3 * sl + 2];
                    // x0 y0 z0 x1 | y1 z1 x2 y2 | z2 x3 y3 z3
                    const float d0[4]  = {A.x, A.w, B.z, C.y};
                    const float d1[4]  = {A.y, B.x, B.w, C.z};
                    const float d2e[4] = {A.z, B.y, C.x, C.w};
                    float sqd[4];
#pragma unroll
                    for (int j = 0; j < 4; ++j)
                        sqd[j] = __fadd_rn(
                            __fadd_rn(__fmul_rn(d0[j], d0[j]),
                                      __fmul_rn(d1[j], d1[j])),
                            __fmul_rn(d2e[j], d2e[j]));

                    const int c = cbase + 4 * (g0 + sl);
#pragma unroll
                    for (int rr = 0; rr < ROWS; ++rr) {
                        float mv[4], wv[4];
                        int cc = 0;
#pragma unroll
                        for (int j = 0; j < 4; ++j) {
                            const float dot = __fmaf_rn(q2[rr], d2e[j],
                                                __fmaf_rn(q1[rr], d1[j],
                                                  __fmul_rn(q0[rr], d0[j])));
                            float v = __fsub_rn(__fadd_rn(sqq[rr], sqd[j]),
                                                __fmul_rn(2.0f, dot));
                            v = fmaxf(v, 0.0f);
                            const bool in = (v <= r2);
                            mv[j] = in ? 1.0f : 0.0f;
                            wv[j] = in ? v : 0.0f;
                            cc += in ? 1 : 0;
                        }
                        if (pass == 0) cnt[rr] += cc;
                        floatx4 mvec = {mv[0], mv[1], mv[2], mv[3]};
                        floatx4 wvec = {wv[0], wv[1], wv[2], wv[3]};
                        __builtin_nontemporal_store(
                            mvec, reinterpret_cast<floatx4*>(mrow[rr] + c));
                        __builtin_nontemporal_store(
                            wvec, reinterpret_cast<floatx4*>(wrow[rr] + c));
                    }
                }
            }
        }
    }

    // Per-row block count reduction: wave shuffle, then LDS across 4 waves.
    if (tid < ROWS) lds_cnt[tid] = 0;
    __syncthreads();
#pragma unroll
    for (int rr = 0; rr < ROWS; ++rr) {
        int c = cnt[rr];
        for (int off = 32; off > 0; off >>= 1) c += __shfl_down(c, off);
        if ((tid & 63) == 0) atomicAdd(&lds_cnt[rr], c);
    }
    __syncthreads();
    if (tid < ROWS) counts[m0 + tid] = lds_cnt[tid];
}

// Single-block exclusive scan of counts[M] -> row_splits[M+1] (as floats).
__global__ __launch_bounds__(256) void scan_kernel(
    const int* __restrict__ counts, float* __restrict__ out, int M)
{
    __shared__ int sums[256];
    const int t = threadIdx.x;
    const int CH = (M + 255) / 256;  // 48 for M=12288
    const int base = t * CH;

    int local[64];  // CH <= 64 assumed
    int s = 0;
    for (int i = 0; i < CH; ++i) {
        const int v = (base + i < M) ? counts[base + i] : 0;
        local[i] = v;
        s += v;
    }
    sums[t] = s;
    __syncthreads();
    for (int off = 1; off < 256; off <<= 1) {
        const int v = (t >= off) ? sums[t - off] : 0;
        __syncthreads();
        sums[t] += v;
        __syncthreads();
    }
    int prefix = sums[t] - s;  // exclusive prefix of this thread's chunk
    for (int i = 0; i < CH; ++i) {
        if (base + i < M) out[base + i] = (float)prefix;
        prefix += local[i];
    }
    if (t == 255) out[M] = (float)prefix;  // total
}

extern "C" void kernel_launch(void* const* d_in, const int* in_sizes, int n_in,
                              void* d_out, int out_size, void* d_ws, size_t ws_size,
                              hipStream_t stream) {
    const float* data    = (const float*)d_in[0];
    const float* queries = (const float*)d_in[1];
    const float* radius  = (const float*)d_in[2];

    const int N = in_sizes[0] / 3;  // 12288
    const int M = in_sizes[1] / 3;  // 12288

    float* out = (float*)d_out;
    int* counts = (int*)d_ws;

    const long long mask_off = (long long)M + 1;
    const long long w_off = mask_off + (long long)M * N;

    // First column c such that (mask_off + c) is 16-word (64B) aligned.
    const int cbase = (int)((16 - (mask_off & 15)) & 15);

    // npass = 3 (runtime arg: forbids unroll/DSE across passes).
    nbr_kernel<<<M / ROWS, BLK, 0, stream>>>(data, queries, radius, out, counts,
                                             N, mask_off, w_off, cbase, 3);
    scan_kernel<<<1, 256, 0, stream>>>(counts, out, M);
}

// Round 7
// 1239.841 us; speedup vs baseline: 1.3724x; 1.3724x over previous
//
#include <hip/hip_runtime.h>

// Neighbor search: M=N=12288, DIM=3.
// d_out layout (float32, flat):
//   [0 .. M]                row_splits
//   [M+1 .. M+1+M*N)        mask (0.0 / 1.0)
//   [M+1+M*N .. +2*M*N)     weights (d2 if mask else 0)
//
// R8 = restore of the best verified kernel (R4, 1240.1us) after the
// R6/R7 multi-pass diagnostics. Final model, from T(npass)={1240,1474,1702}
// being linear (T = 1009 + 231*npass) AND nbr never surfacing in top-5 even
// at npass=3 (~690us < 768us fills):
//   - nbr itself runs ~231us = 5.2 TB/s effective write BW = 84% of the
//     6.25 TB/s the harness's own poison fill demonstrates. Near roofline.
//   - ~1010us of the timed window is harness-fixed (one ~775us 4.83GB
//     poison fill + ~235us of other reset dispatches).
//   - Remaining controllable headroom ~37us (3% of total) == noise band.
// The R2-R5 store-side campaign (width/alignment/nt/write-order) was
// neutral because the store stream was never the 2.6 TB/s bottleneck the
// window arithmetic suggested — the window contained ~1010us of fixed
// harness work that masked a ~231us kernel.
//
// Bit-exactness vs numpy/BLAS fp32:
//   sq = (x0*x0 + x1*x1) + x2*x2
//   dot = fma(q2,d2, fma(q1,d1, q0*d0))
//   d2  = (sq_q + sq_d) - 2*dot ; max(d2,0) ; mask = d2 <= r*r

#define BLK 256
#define ROWS 8
#define GTILE 512             // float4 column-groups per LDS tile
#define TWORDS (GTILE * 12)   // 6144 floats = 24 KB

typedef float floatx4 __attribute__((ext_vector_type(4)));

__global__ __launch_bounds__(BLK) void nbr_kernel(
    const float* __restrict__ data,
    const float* __restrict__ queries,
    const float* __restrict__ radius_p,
    float* __restrict__ out,
    int* __restrict__ counts,
    int N, long long mask_off, long long w_off, int cbase)
{
    __shared__ float4 tile4[GTILE * 3];
    float* tile = reinterpret_cast<float*>(tile4);
    __shared__ int lds_cnt[ROWS];

    const int tid = threadIdx.x;
    const int m0 = blockIdx.x * ROWS;

    const float r = radius_p[0];
    const float r2 = __fmul_rn(r, r);

    float q0[ROWS], q1[ROWS], q2[ROWS], sqq[ROWS];
#pragma unroll
    for (int rr = 0; rr < ROWS; ++rr) {
        q0[rr] = queries[3 * (m0 + rr) + 0];
        q1[rr] = queries[3 * (m0 + rr) + 1];
        q2[rr] = queries[3 * (m0 + rr) + 2];
        sqq[rr] = __fadd_rn(__fadd_rn(__fmul_rn(q0[rr], q0[rr]),
                                      __fmul_rn(q1[rr], q1[rr])),
                            __fmul_rn(q2[rr], q2[rr]));
    }

    float* mrow[ROWS];
    float* wrow[ROWS];
#pragma unroll
    for (int rr = 0; rr < ROWS; ++rr) {
        mrow[rr] = out + mask_off + (long long)(m0 + rr) * N;
        wrow[rr] = out + w_off    + (long long)(m0 + rr) * N;
    }

    int cnt[ROWS];
#pragma unroll
    for (int rr = 0; rr < ROWS; ++rr) cnt[rr] = 0;

    // Aligned groups: cols cbase+4g, g in [0, ng). (mask_off+cbase) % 16 == 0
    // and N % 16 == 0, so each wave burst of 64 float4 lanes is 16 aligned,
    // fully-covered 64B lines.
    const int ng = (N - cbase) / 4;
    const int nspec = N - 4 * ng;  // cols 0..cbase-1 and cbase+4*ng..N-1

    // Scalar prologue for the non-line-aligned columns (nspec <= 16 threads).
    if (tid < nspec) {
        const int c = (tid < cbase) ? tid : (cbase + 4 * ng + (tid - cbase));
        const float d0  = data[3 * c + 0];
        const float d1  = data[3 * c + 1];
        const float d2e = data[3 * c + 2];
        const float sqd = __fadd_rn(
            __fadd_rn(__fmul_rn(d0, d0), __fmul_rn(d1, d1)),
            __fmul_rn(d2e, d2e));
#pragma unroll
        for (int rr = 0; rr < ROWS; ++rr) {
            const float dot = __fmaf_rn(q2[rr], d2e,
                                __fmaf_rn(q1[rr], d1, __fmul_rn(q0[rr], d0)));
            float v = __fsub_rn(__fadd_rn(sqq[rr], sqd), __fmul_rn(2.0f, dot));
            v = fmaxf(v, 0.0f);
            const bool in = (v <= r2);
            mrow[rr][c] = in ? 1.0f : 0.0f;
            wrow[rr][c] = in ? v : 0.0f;
            cnt[rr] += in ? 1 : 0;
        }
    }

    // Main loop over column-group tiles.
    for (int g0 = 0; g0 < ng; g0 += GTILE) {
        const int ngt = min(GTILE, ng - g0);
        const long long W0 = 3LL * (cbase + 4LL * (long long)g0);
        const int lim = 12 * ngt;

        __syncthreads();  // previous tile's readers done before overwrite
        if (lim == TWORDS) {
#pragma unroll
            for (int k = 0; k < TWORDS / BLK; ++k)
                tile[k * BLK + tid] = data[W0 + k * BLK + tid];
        } else {
            for (int w = tid; w < lim; w += BLK)
                tile[w] = data[W0 + w];
        }
        __syncthreads();

#pragma unroll
        for (int k = 0; k < GTILE / BLK; ++k) {
            const int sl = k * BLK + tid;
            if (sl < ngt) {
                // 3x aligned ds_read_b128; banks balanced (2 lanes/bank).
                const float4 A = tile4[3 * sl + 0];
                const float4 B = tile4[3 * sl + 1];
                const float4 C = tile4[3 * sl + 2];
                // xyz interleave: x0 y0 z0 x1 | y1 z1 x2 y2 | z2 x3 y3 z3
                const float d0[4]  = {A.x, A.w, B.z, C.y};
                const float d1[4]  = {A.y, B.x, B.w, C.z};
                const float d2e[4] = {A.z, B.y, C.x, C.w};
                float sqd[4];
#pragma unroll
                for (int j = 0; j < 4; ++j)
                    sqd[j] = __fadd_rn(
                        __fadd_rn(__fmul_rn(d0[j], d0[j]),
                                  __fmul_rn(d1[j], d1[j])),
                        __fmul_rn(d2e[j], d2e[j]));

                const int c = cbase + 4 * (g0 + sl);
#pragma unroll
                for (int rr = 0; rr < ROWS; ++rr) {
                    float mv[4], wv[4];
                    int cc = 0;
#pragma unroll
                    for (int j = 0; j < 4; ++j) {
                        const float dot = __fmaf_rn(q2[rr], d2e[j],
                                            __fmaf_rn(q1[rr], d1[j],
                                              __fmul_rn(q0[rr], d0[j])));
                        float v = __fsub_rn(__fadd_rn(sqq[rr], sqd[j]),
                                            __fmul_rn(2.0f, dot));
                        v = fmaxf(v, 0.0f);
                        const bool in = (v <= r2);
                        mv[j] = in ? 1.0f : 0.0f;
                        wv[j] = in ? v : 0.0f;
                        cc += in ? 1 : 0;
                    }
                    cnt[rr] += cc;
                    // Full-line, 64B-aligned, streaming (never re-read):
                    floatx4 mvec = {mv[0], mv[1], mv[2], mv[3]};
                    floatx4 wvec = {wv[0], wv[1], wv[2], wv[3]};
                    __builtin_nontemporal_store(
                        mvec, reinterpret_cast<floatx4*>(mrow[rr] + c));
                    __builtin_nontemporal_store(
                        wvec, reinterpret_cast<floatx4*>(wrow[rr] + c));
                }
            }
        }
    }

    // Per-row block count reduction: wave shuffle, then LDS across 4 waves.
    if (tid < ROWS) lds_cnt[tid] = 0;
    __syncthreads();
#pragma unroll
    for (int rr = 0; rr < ROWS; ++rr) {
        int c = cnt[rr];
        for (int off = 32; off > 0; off >>= 1) c += __shfl_down(c, off);
        if ((tid & 63) == 0) atomicAdd(&lds_cnt[rr], c);
    }
    __syncthreads();
    if (tid < ROWS) counts[m0 + tid] = lds_cnt[tid];
}

// Single-block exclusive scan of counts[M] -> row_splits[M+1] (as floats).
__global__ __launch_bounds__(256) void scan_kernel(
    const int* __restrict__ counts, float* __restrict__ out, int M)
{
    __shared__ int sums[256];
    const int t = threadIdx.x;
    const int CH = (M + 255) / 256;  // 48 for M=12288
    const int base = t * CH;

    int local[64];  // CH <= 64 assumed
    int s = 0;
    for (int i = 0; i < CH; ++i) {
        const int v = (base + i < M) ? counts[base + i] : 0;
        local[i] = v;
        s += v;
    }
    sums[t] = s;
    __syncthreads();
    for (int off = 1; off < 256; off <<= 1) {
        const int v = (t >= off) ? sums[t - off] : 0;
        __syncthreads();
        sums[t] += v;
        __syncthreads();
    }
    int prefix = sums[t] - s;  // exclusive prefix of this thread's chunk
    for (int i = 0; i < CH; ++i) {
        if (base + i < M) out[base + i] = (float)prefix;
        prefix += local[i];
    }
    if (t == 255) out[M] = (float)prefix;  // total
}

extern "C" void kernel_launch(void* const* d_in, const int* in_sizes, int n_in,
                              void* d_out, int out_size, void* d_ws, size_t ws_size,
                              hipStream_t stream) {
    const float* data    = (const float*)d_in[0];
    const float* queries = (const float*)d_in[1];
    const float* radius  = (const float*)d_in[2];

    const int N = in_sizes[0] / 3;  // 12288
    const int M = in_sizes[1] / 3;  // 12288

    float* out = (float*)d_out;
    int* counts = (int*)d_ws;

    const long long mask_off = (long long)M + 1;
    const long long w_off = mask_off + (long long)M * N;

    // First column c such that (mask_off + c) is 16-word (64B) aligned.
    // N % 16 == 0 and (M*N) % 16 == 0, so the same cbase aligns every row
    // of both the mask and the weights regions.
    const int cbase = (int)((16 - (mask_off & 15)) & 15);

    // M = 12288 divisible by ROWS = 8 -> grid 1536 = 6 blocks/CU x 256 CU.
    nbr_kernel<<<M / ROWS, BLK, 0, stream>>>(data, queries, radius, out, counts,
                                             N, mask_off, w_off, cbase);
    scan_kernel<<<1, 256, 0, stream>>>(counts, out, M);
}